// Round 1
// baseline (71.415 us; speedup 1.0000x reference)
//
#include <hip/hip_runtime.h>
#include <hip/hip_bf16.h>

// Problem constants (fixed by the reference)
#define BB 4096   // batch
#define DD 64     // event dim
#define HH 512    // hidden

typedef short short8 __attribute__((ext_vector_type(8)));   // 8 bf16 (4 VGPRs)
typedef float f32x4  __attribute__((ext_vector_type(4)));

// ---------------------------------------------------------------------------
// prep_convert: bf16 conversions + transposes + effective bias
//   sec 0: z  [4096,64] f32 -> bf16                         (262144)
//   sec 1: W2t[n*512+k] = bf16(W2[k*512+n])                 (262144)
//   sec 2: W1t[n*64+k]  = bf16(W1[k*512+n])   (k<64)        (32768)
//   sec 3: W3t[n*512+k] = bf16(W3[k*64+n])                  (32768)
//   sec 4: b1eff[j] = b1[j] + t*W1[64*512+j]                (512)
// ---------------------------------------------------------------------------
__global__ __launch_bounds__(256) void prep_convert(
    const float* __restrict__ z, const float* __restrict__ W1,
    const float* __restrict__ W2, const float* __restrict__ W3,
    const float* __restrict__ b1, const float* __restrict__ t,
    __hip_bfloat16* __restrict__ z_b, __hip_bfloat16* __restrict__ W1t,
    __hip_bfloat16* __restrict__ W2t, __hip_bfloat16* __restrict__ W3t,
    float* __restrict__ b1eff)
{
    int idx = blockIdx.x * 256 + threadIdx.x;
    int sec = blockIdx.y;
    if (sec == 0) {
        z_b[idx] = __float2bfloat16(z[idx]);
    } else if (sec == 1) {
        int n = idx >> 9, k = idx & 511;
        W2t[idx] = __float2bfloat16(W2[k * HH + n]);
    } else if (sec == 2) {
        if (idx < 32768) {
            int n = idx >> 6, k = idx & 63;
            W1t[idx] = __float2bfloat16(W1[k * HH + n]);
        }
    } else if (sec == 3) {
        if (idx < 32768) {
            int n = idx >> 9, k = idx & 511;
            W3t[idx] = __float2bfloat16(W3[k * DD + n]);
        }
    } else {
        if (idx < HH) b1eff[idx] = b1[idx] + t[0] * W1[64 * HH + idx];
    }
}

// ---------------------------------------------------------------------------
// prep_P: Pt[k*512+j] = bf16( W2[j,k] * sum_d W1[d,j]*W3[k,d] )
// (Bt layout for the trace GEMM: rows are output col k, cols are reduce dim j)
// ---------------------------------------------------------------------------
__global__ __launch_bounds__(256) void prep_P(
    const float* __restrict__ W1, const float* __restrict__ W2,
    const float* __restrict__ W3, __hip_bfloat16* __restrict__ Pt)
{
    int idx = blockIdx.x * 256 + threadIdx.x;   // 262144
    int k = idx >> 9, j = idx & 511;
    float s = 0.f;
#pragma unroll
    for (int d = 0; d < DD; ++d) s += W1[d * HH + j] * W3[k * DD + d];
    Pt[idx] = __float2bfloat16(W2[j * HH + k] * s);
}

// ---------------------------------------------------------------------------
// GEMM: C[M,N] = A[M,K] * B[K,N]; A row-major bf16, Bt = B^T row-major [N,K].
// Block = 64x64 tile, 4 waves in 2x2, each wave 32x32 via 2x2 mfma 16x16x32.
// EPI 0: h = tanh(acc + bias[col]); outH=bf16(h); outA=bf16(1-h*h)
// EPI 1: outF[row*N+col] = acc + bias[col]                  (fp32, v output)
// EPI 2: outF[row*N+col] = acc * (float)outA[row*N+col]     (Vb = V .* bsq)
// ---------------------------------------------------------------------------
template <int EPI>
__global__ __launch_bounds__(256) void gemm_kernel(
    const __hip_bfloat16* __restrict__ A,
    const __hip_bfloat16* __restrict__ Bt,
    const float* __restrict__ bias, int K, int N,
    float* __restrict__ outF,
    __hip_bfloat16* __restrict__ outH,
    __hip_bfloat16* __restrict__ outA)
{
    const int tid  = threadIdx.x;
    const int wid  = tid >> 6;
    const int lane = tid & 63;
    const int r    = lane & 15;
    const int kq   = lane >> 4;        // 0..3
    const int wm   = (wid >> 1) * 32;
    const int wn   = (wid & 1) * 32;
    const int bm   = blockIdx.x * 64;
    const int bn   = blockIdx.y * 64;

    f32x4 acc[2][2] = {};

    const int arow0 = bm + wm + r;
    const int bcol0 = bn + wn + r;
    const __hip_bfloat16* pa0 = A  + (size_t)arow0 * K + kq * 8;
    const __hip_bfloat16* pa1 = A  + (size_t)(arow0 + 16) * K + kq * 8;
    const __hip_bfloat16* pb0 = Bt + (size_t)bcol0 * K + kq * 8;
    const __hip_bfloat16* pb1 = Bt + (size_t)(bcol0 + 16) * K + kq * 8;

    for (int k0 = 0; k0 < K; k0 += 32) {
        short8 a0 = *(const short8*)(pa0 + k0);
        short8 a1 = *(const short8*)(pa1 + k0);
        short8 b0 = *(const short8*)(pb0 + k0);
        short8 b1 = *(const short8*)(pb1 + k0);
        acc[0][0] = __builtin_amdgcn_mfma_f32_16x16x32_bf16(a0, b0, acc[0][0], 0, 0, 0);
        acc[0][1] = __builtin_amdgcn_mfma_f32_16x16x32_bf16(a0, b1, acc[0][1], 0, 0, 0);
        acc[1][0] = __builtin_amdgcn_mfma_f32_16x16x32_bf16(a1, b0, acc[1][0], 0, 0, 0);
        acc[1][1] = __builtin_amdgcn_mfma_f32_16x16x32_bf16(a1, b1, acc[1][1], 0, 0, 0);
    }

#pragma unroll
    for (int mi = 0; mi < 2; ++mi) {
#pragma unroll
        for (int ni = 0; ni < 2; ++ni) {
#pragma unroll
            for (int v = 0; v < 4; ++v) {
                int row = bm + wm + mi * 16 + kq * 4 + v;
                int col = bn + wn + ni * 16 + r;
                float val = acc[mi][ni][v];
                size_t o = (size_t)row * N + col;
                if (EPI == 0) {
                    val += bias[col];
                    float h = tanhf(val);
                    outH[o] = __float2bfloat16(h);
                    outA[o] = __float2bfloat16(1.0f - h * h);
                } else if (EPI == 1) {
                    outF[o] = val + bias[col];
                } else {
                    float bs = __bfloat162float(outA[o]);
                    outF[o] = val * bs;
                }
            }
        }
    }
}

// ---------------------------------------------------------------------------
// reduce_trace: out[row] = -sum_k Vb[row,k]   (one wave per row)
// ---------------------------------------------------------------------------
__global__ __launch_bounds__(256) void reduce_trace(
    const float* __restrict__ Vb, float* __restrict__ out)
{
    int wid = threadIdx.x >> 6, lane = threadIdx.x & 63;
    int row = blockIdx.x * 4 + wid;
    const float4* p4 = (const float4*)(Vb + (size_t)row * HH);
    float4 u = p4[lane * 2];
    float4 w = p4[lane * 2 + 1];
    float s = u.x + u.y + u.z + u.w + w.x + w.y + w.z + w.w;
#pragma unroll
    for (int off = 32; off; off >>= 1) s += __shfl_down(s, off, 64);
    if (lane == 0) out[row] = -s;
}

extern "C" void kernel_launch(void* const* d_in, const int* in_sizes, int n_in,
                              void* d_out, int out_size, void* d_ws, size_t ws_size,
                              hipStream_t stream)
{
    const float* z  = (const float*)d_in[0];
    // d_in[1] = log_pz (unused by reference outputs)
    const float* t  = (const float*)d_in[2];
    const float* W1 = (const float*)d_in[3];
    const float* b1 = (const float*)d_in[4];
    const float* W2 = (const float*)d_in[5];
    const float* b2 = (const float*)d_in[6];
    const float* W3 = (const float*)d_in[7];
    const float* b3 = (const float*)d_in[8];
    float* out = (float*)d_out;                 // v [4096*64] then dlogp [4096]

    char* w = (char*)d_ws;
    auto alloc = [&](size_t bytes) {
        char* p = w;
        w += (bytes + 255) & ~(size_t)255;
        return p;
    };
    __hip_bfloat16* z_b   = (__hip_bfloat16*)alloc((size_t)BB * DD * 2);
    __hip_bfloat16* W1t   = (__hip_bfloat16*)alloc((size_t)HH * DD * 2);
    __hip_bfloat16* W2t   = (__hip_bfloat16*)alloc((size_t)HH * HH * 2);
    __hip_bfloat16* W3t   = (__hip_bfloat16*)alloc((size_t)DD * HH * 2);
    __hip_bfloat16* Pt    = (__hip_bfloat16*)alloc((size_t)HH * HH * 2);
    float*          b1eff = (float*)alloc((size_t)HH * 4);
    __hip_bfloat16* h1b   = (__hip_bfloat16*)alloc((size_t)BB * HH * 2);
    __hip_bfloat16* ab    = (__hip_bfloat16*)alloc((size_t)BB * HH * 2);
    __hip_bfloat16* h2b   = (__hip_bfloat16*)alloc((size_t)BB * HH * 2);
    __hip_bfloat16* bsb   = (__hip_bfloat16*)alloc((size_t)BB * HH * 2);
    float*          Vb    = (float*)alloc((size_t)BB * HH * 4);

    // 1) conversions / transposes / effective bias
    prep_convert<<<dim3(1024, 5), 256, 0, stream>>>(z, W1, W2, W3, b1, t,
                                                    z_b, W1t, W2t, W3t, b1eff);
    // 2) Pt[k,j] = W2[j,k] * sum_d W1[d,j] W3[k,d]
    prep_P<<<1024, 256, 0, stream>>>(W1, W2, W3, Pt);
    // 3) layer 1: h1 = tanh(z*W1z + b1eff); a = 1-h1^2
    gemm_kernel<0><<<dim3(BB / 64, HH / 64), 256, 0, stream>>>(
        z_b, W1t, b1eff, DD, HH, nullptr, h1b, ab);
    // 4) layer 2: h2 = tanh(h1*W2 + b2); bsq = 1-h2^2
    gemm_kernel<0><<<dim3(BB / 64, HH / 64), 256, 0, stream>>>(
        h1b, W2t, b2, HH, HH, nullptr, h2b, bsb);
    // 5) layer 3: v = h2*W3 + b3  -> out[0 : B*D]
    gemm_kernel<1><<<dim3(BB / 64, DD / 64), 256, 0, stream>>>(
        h2b, W3t, b3, HH, DD, out, nullptr, nullptr);
    // 6) Vb = (a*P) .* bsq
    gemm_kernel<2><<<dim3(BB / 64, HH / 64), 256, 0, stream>>>(
        ab, Pt, nullptr, HH, HH, Vb, nullptr, bsb);
    // 7) dlogp_dt[i] = -sum_k Vb[i,k]  -> out[B*D + i]
    reduce_trace<<<BB / 4, 256, 0, stream>>>(Vb, out + (size_t)BB * DD);
}

// Round 2
// 40.793 us; speedup vs baseline: 1.7507x; 1.7507x over previous
//
#include <hip/hip_runtime.h>
#include <hip/hip_bf16.h>

#define BB 4096   // batch
#define DD 64     // event dim
#define HH 512    // hidden

typedef short short8 __attribute__((ext_vector_type(8)));   // 8 bf16
typedef float f32x4  __attribute__((ext_vector_type(4)));
typedef __hip_bfloat16 bf16;

// async global->LDS, 16B per lane; LDS dest is wave-uniform base + lane*16
#define GLOAD_LDS16(gp, lp)                                                \
  __builtin_amdgcn_global_load_lds(                                        \
      (const __attribute__((address_space(1))) void*)(gp),                 \
      (__attribute__((address_space(3))) void*)(lp), 16, 0, 0)

// ---------------------------------------------------------------------------
// prep kernel: grid (256, 6) x 256 threads
//  y0: z f32 -> bf16 (vectorized)
//  y1: W2t[n][k] = bf16(W2[k][n])        (32x32 LDS-tiled transpose, 256 tiles)
//  y2: W1t[j][d] = bf16(W1[d][j]), d<64  (32 tiles)
//  y3: W3t[e][k] = bf16(W3[k][e])        (32 tiles)
//  y4: Pt[k][j]  = bf16(W2[j][k] * sum_d W1[d][j]*W3[k][d])   (64 blocks)
//  y5: b1eff[j] = b1[j] + t*W1[64][j]; zero trace-out region
// ---------------------------------------------------------------------------
__global__ __launch_bounds__(256) void prep_kernel(
    const float* __restrict__ z, const float* __restrict__ t,
    const float* __restrict__ W1, const float* __restrict__ b1,
    const float* __restrict__ W2, const float* __restrict__ W3,
    bf16* __restrict__ z_b, bf16* __restrict__ W1t, bf16* __restrict__ W2t,
    bf16* __restrict__ W3t, bf16* __restrict__ Pt,
    float* __restrict__ b1eff, float* __restrict__ out_tr)
{
    __shared__ float tile[32][33];
    const int tid = threadIdx.x;
    const int bx  = blockIdx.x;
    const int sec = blockIdx.y;
    const int tx = tid & 31, ty = tid >> 5;   // 32 x 8

    if (sec == 0) {
        int i = (bx * 256 + tid) * 4;
        float4 v = *(const float4*)(z + i);
        z_b[i + 0] = __float2bfloat16(v.x);
        z_b[i + 1] = __float2bfloat16(v.y);
        z_b[i + 2] = __float2bfloat16(v.z);
        z_b[i + 3] = __float2bfloat16(v.w);
    } else if (sec == 1) {
        int r0 = (bx >> 4) * 32, c0 = (bx & 15) * 32;
#pragma unroll
        for (int i = 0; i < 32; i += 8)
            tile[ty + i][tx] = W2[(size_t)(r0 + ty + i) * HH + c0 + tx];
        __syncthreads();
#pragma unroll
        for (int i = 0; i < 32; i += 8)
            W2t[(size_t)(c0 + ty + i) * HH + r0 + tx] = __float2bfloat16(tile[tx][ty + i]);
    } else if (sec == 2) {
        if (bx < 32) {
            int r0 = (bx >> 4) * 32, c0 = (bx & 15) * 32;   // rows of W1 (d), cols (j)
#pragma unroll
            for (int i = 0; i < 32; i += 8)
                tile[ty + i][tx] = W1[(size_t)(r0 + ty + i) * HH + c0 + tx];
            __syncthreads();
#pragma unroll
            for (int i = 0; i < 32; i += 8)
                W1t[(size_t)(c0 + ty + i) * DD + r0 + tx] = __float2bfloat16(tile[tx][ty + i]);
        }
    } else if (sec == 3) {
        if (bx < 32) {
            int r0 = (bx >> 1) * 32, c0 = (bx & 1) * 32;    // rows of W3 (k), cols (e)
#pragma unroll
            for (int i = 0; i < 32; i += 8)
                tile[ty + i][tx] = W3[(size_t)(r0 + ty + i) * DD + c0 + tx];
            __syncthreads();
#pragma unroll
            for (int i = 0; i < 32; i += 8)
                W3t[(size_t)(c0 + ty + i) * HH + r0 + tx] = __float2bfloat16(tile[tx][ty + i]);
        }
    } else if (sec == 4) {
        if (bx < 64) {
            int k0 = bx * 8;
            int j0 = tid * 2;
            float acc0[8] = {}, acc1[8] = {};
            for (int d = 0; d < 64; ++d) {
                float w1a = W1[(size_t)d * HH + j0];
                float w1b = W1[(size_t)d * HH + j0 + 1];
#pragma unroll
                for (int kk = 0; kk < 8; ++kk) {
                    float w3 = W3[(size_t)(k0 + kk) * DD + d];
                    acc0[kk] += w1a * w3;
                    acc1[kk] += w1b * w3;
                }
            }
#pragma unroll
            for (int kk = 0; kk < 8; ++kk) {
                int k = k0 + kk;
                Pt[(size_t)k * HH + j0]     = __float2bfloat16(acc0[kk] * W2[(size_t)j0 * HH + k]);
                Pt[(size_t)k * HH + j0 + 1] = __float2bfloat16(acc1[kk] * W2[(size_t)(j0 + 1) * HH + k]);
            }
        }
    } else {
        if (bx == 0) {
            float tv = t[0];
            b1eff[tid]       = b1[tid]       + tv * W1[(size_t)64 * HH + tid];
            b1eff[tid + 256] = b1[tid + 256] + tv * W1[(size_t)64 * HH + tid + 256];
        } else if (bx < 5) {
            int i = ((bx - 1) * 256 + tid) * 4;
            *(float4*)(out_tr + i) = make_float4(0.f, 0.f, 0.f, 0.f);
        }
    }
}

// ---------------------------------------------------------------------------
// GEMM body: C[M,N] = A[M,K] * Bt[N,K]^T. 64x64 block tile, BK=64, dbuf LDS
// via global_load_lds(16B) with XOR chunk-swizzle (source-permute + read-XOR).
// 4 waves 2x2, each wave 32x32 via 2x2 mfma_f32_16x16x32_bf16.
//  EPI 0: h = tanh(acc+bias[col]) -> outH; 1-h^2 -> outA
//  EPI 1: outF = acc + bias[col]
//  EPI 2: trace: p_row = sum_col acc*bs; shfl-reduce; atomicAdd(outTr+row,-p)
// ---------------------------------------------------------------------------
template <int EPI, int K, int N>
__device__ __forceinline__ void gemm_body(
    const bf16* __restrict__ A, const bf16* __restrict__ Bt,
    const float* __restrict__ bias,
    bf16* __restrict__ outH, bf16* __restrict__ outA,
    const bf16* __restrict__ bs, float* __restrict__ outF,
    float* __restrict__ outTr,
    int bm, int bn, bf16* As, bf16* Bs)
{
    const int tid  = threadIdx.x;
    const int wid  = tid >> 6;
    const int lane = tid & 63;
    const int r    = lane & 15;
    const int kq   = lane >> 4;
    const int wm   = (wid >> 1) * 32;
    const int wn   = (wid & 1) * 32;

    // LDS read offsets (bf16 elements), swizzled chunk addressing
    int offA[2][2], offB[2][2];
#pragma unroll
    for (int mi = 0; mi < 2; ++mi) {
        int row = wm + mi * 16 + r;
#pragma unroll
        for (int ks = 0; ks < 2; ++ks)
            offA[mi][ks] = row * 64 + ((((ks * 4 + kq) ^ (row & 7))) << 3);
    }
#pragma unroll
    for (int ni = 0; ni < 2; ++ni) {
        int row = wn + ni * 16 + r;
#pragma unroll
        for (int ks = 0; ks < 2; ++ks)
            offB[ni][ks] = row * 64 + ((((ks * 4 + kq) ^ (row & 7))) << 3);
    }

    auto stage = [&](int b, int k0) {
#pragma unroll
        for (int rnd = 0; rnd < 2; ++rnd) {
            int i = rnd * 256 + tid;
            int row = i >> 3;
            int c = ((i & 7) ^ (row & 7)) << 3;      // inverse-swizzled source col
            GLOAD_LDS16(A  + (size_t)(bm + row) * K + k0 + c, As + b * 4096 + i * 8);
            GLOAD_LDS16(Bt + (size_t)(bn + row) * K + k0 + c, Bs + b * 4096 + i * 8);
        }
    };

    f32x4 acc[2][2] = {};
    constexpr int NS = K / 64;

    stage(0, 0);
    int buf = 0;
    for (int s = 0; s < NS; ++s) {
        __syncthreads();                       // drains vmcnt -> staged data valid
        if (s + 1 < NS) stage(buf ^ 1, (s + 1) * 64);
        const bf16* a_base = As + buf * 4096;
        const bf16* b_base = Bs + buf * 4096;
        short8 af[2][2], bfr[2][2];
#pragma unroll
        for (int mi = 0; mi < 2; ++mi)
#pragma unroll
            for (int ks = 0; ks < 2; ++ks)
                af[mi][ks] = *(const short8*)(a_base + offA[mi][ks]);
#pragma unroll
        for (int ni = 0; ni < 2; ++ni)
#pragma unroll
            for (int ks = 0; ks < 2; ++ks)
                bfr[ni][ks] = *(const short8*)(b_base + offB[ni][ks]);
#pragma unroll
        for (int ks = 0; ks < 2; ++ks)
#pragma unroll
            for (int mi = 0; mi < 2; ++mi)
#pragma unroll
                for (int ni = 0; ni < 2; ++ni)
                    acc[mi][ni] = __builtin_amdgcn_mfma_f32_16x16x32_bf16(
                        af[mi][ks], bfr[ni][ks], acc[mi][ni], 0, 0, 0);
        __syncthreads();
        buf ^= 1;
    }

    // epilogue
#pragma unroll
    for (int mi = 0; mi < 2; ++mi) {
        if (EPI == 2) {
#pragma unroll
            for (int v = 0; v < 4; ++v) {
                int row = bm + wm + mi * 16 + kq * 4 + v;
                float p = 0.f;
#pragma unroll
                for (int ni = 0; ni < 2; ++ni) {
                    int col = bn + wn + ni * 16 + r;
                    float bsv = __bfloat162float(bs[(size_t)row * N + col]);
                    p += acc[mi][ni][v] * bsv;
                }
                p += __shfl_xor(p, 1);
                p += __shfl_xor(p, 2);
                p += __shfl_xor(p, 4);
                p += __shfl_xor(p, 8);
                if (r == 0) atomicAdd(outTr + row, -p);
            }
        } else {
#pragma unroll
            for (int ni = 0; ni < 2; ++ni) {
#pragma unroll
                for (int v = 0; v < 4; ++v) {
                    int row = bm + wm + mi * 16 + kq * 4 + v;
                    int col = bn + wn + ni * 16 + r;
                    float val = acc[mi][ni][v] + bias[col];
                    size_t o = (size_t)row * N + col;
                    if (EPI == 0) {
                        float h = tanhf(val);
                        outH[o] = __float2bfloat16(h);
                        outA[o] = __float2bfloat16(1.0f - h * h);
                    } else {
                        outF[o] = val;
                    }
                }
            }
        }
    }
}

template <int EPI, int K, int N>
__global__ __launch_bounds__(256) void gemm_kernel(
    const bf16* __restrict__ A, const bf16* __restrict__ Bt,
    const float* __restrict__ bias,
    bf16* __restrict__ outH, bf16* __restrict__ outA,
    const bf16* __restrict__ bs, float* __restrict__ outF,
    float* __restrict__ outTr)
{
    __shared__ alignas(16) bf16 As[2 * 4096];
    __shared__ alignas(16) bf16 Bs[2 * 4096];
    gemm_body<EPI, K, N>(A, Bt, bias, outH, outA, bs, outF, outTr,
                         blockIdx.x * 64, blockIdx.y * 64, As, Bs);
}

// fused: y==8 -> L3 (v = h2@W3 + b3), y<8 -> E (trace = rowsum((a@P).*bsq))
__global__ __launch_bounds__(256) void gemm_fused(
    const bf16* __restrict__ h2b, const bf16* __restrict__ W3t,
    const float* __restrict__ b3, float* __restrict__ outV,
    const bf16* __restrict__ ab, const bf16* __restrict__ Pt,
    const bf16* __restrict__ bsb, float* __restrict__ outTr)
{
    __shared__ alignas(16) bf16 As[2 * 4096];
    __shared__ alignas(16) bf16 Bs[2 * 4096];
    if (blockIdx.y == 8) {
        gemm_body<1, 512, 64>(h2b, W3t, b3, nullptr, nullptr, nullptr, outV,
                              nullptr, blockIdx.x * 64, 0, As, Bs);
    } else {
        gemm_body<2, 512, 512>(ab, Pt, nullptr, nullptr, nullptr, bsb, nullptr,
                               outTr, blockIdx.x * 64, blockIdx.y * 64, As, Bs);
    }
}

extern "C" void kernel_launch(void* const* d_in, const int* in_sizes, int n_in,
                              void* d_out, int out_size, void* d_ws, size_t ws_size,
                              hipStream_t stream)
{
    const float* z  = (const float*)d_in[0];
    const float* t  = (const float*)d_in[2];
    const float* W1 = (const float*)d_in[3];
    const float* b1 = (const float*)d_in[4];
    const float* W2 = (const float*)d_in[5];
    const float* b2 = (const float*)d_in[6];
    const float* W3 = (const float*)d_in[7];
    const float* b3 = (const float*)d_in[8];
    float* out = (float*)d_out;                 // v [4096*64] then dlogp [4096]
    float* out_tr = out + (size_t)BB * DD;

    char* w = (char*)d_ws;
    auto alloc = [&](size_t bytes) {
        char* p = w;
        w += (bytes + 255) & ~(size_t)255;
        return p;
    };
    bf16* z_b   = (bf16*)alloc((size_t)BB * DD * 2);
    bf16* W1t   = (bf16*)alloc((size_t)HH * DD * 2);
    bf16* W2t   = (bf16*)alloc((size_t)HH * HH * 2);
    bf16* W3t   = (bf16*)alloc((size_t)DD * HH * 2);
    bf16* Pt    = (bf16*)alloc((size_t)HH * HH * 2);
    float* b1eff = (float*)alloc((size_t)HH * 4);
    bf16* h1b   = (bf16*)alloc((size_t)BB * HH * 2);
    bf16* ab    = (bf16*)alloc((size_t)BB * HH * 2);
    bf16* h2b   = (bf16*)alloc((size_t)BB * HH * 2);
    bf16* bsb   = (bf16*)alloc((size_t)BB * HH * 2);

    // 1) conversions, transposes, P, b1eff, zero trace
    prep_kernel<<<dim3(256, 6), 256, 0, stream>>>(z, t, W1, b1, W2, W3,
                                                  z_b, W1t, W2t, W3t, Pt,
                                                  b1eff, out_tr);
    // 2) layer 1: h1 = tanh(z@W1 + b1eff)
    gemm_kernel<0, 64, 512><<<dim3(BB / 64, HH / 64), 256, 0, stream>>>(
        z_b, W1t, b1eff, h1b, ab, nullptr, nullptr, nullptr);
    // 3) layer 2: h2 = tanh(h1@W2 + b2)
    gemm_kernel<0, 512, 512><<<dim3(BB / 64, HH / 64), 256, 0, stream>>>(
        h1b, W2t, b2, h2b, bsb, nullptr, nullptr, nullptr);
    // 4) layer 3 (v) fused with trace GEMM (atomic row-sums into out_tr)
    gemm_fused<<<dim3(BB / 64, HH / 64 + 1), 256, 0, stream>>>(
        h2b, W3t, b3, out, ab, Pt, bsb, out_tr);
}